// Round 1
// baseline (2028.754 us; speedup 1.0000x reference)
//
#include <hip/hip_runtime.h>
#include <hip/hip_bf16.h>

using bf16 = __hip_bfloat16;
typedef short s16x8 __attribute__((ext_vector_type(8)));
typedef float f32x4 __attribute__((ext_vector_type(4)));

static constexpr int D  = 2048;
static constexpr int H  = 16;
static constexpr int FF = 8192;
static constexpr int S  = 1024;
static constexpr int NB = 2;        // batch
static constexpr int DH = 128;
static constexpr int L  = 2;
static constexpr int BS = NB * S;   // 2048 tokens
static constexpr int BH = NB * H;   // 32
static constexpr int D3 = 3 * D;    // 6144

// ---------------------------------------------------------------- utilities
__device__ __forceinline__ float wave_sum(float v) {
#pragma unroll
  for (int o = 32; o > 0; o >>= 1) v += __shfl_down(v, o, 64);
  return v;
}
__device__ __forceinline__ float wave_max(float v) {
#pragma unroll
  for (int o = 32; o > 0; o >>= 1) v = fmaxf(v, __shfl_down(v, o, 64));
  return v;
}

__device__ __forceinline__ void gll16(const void* g, void* l) {
  __builtin_amdgcn_global_load_lds(
      (const __attribute__((address_space(1))) unsigned int*)g,
      (__attribute__((address_space(3))) unsigned int*)l, 16, 0, 0);
}

__device__ __forceinline__ float gelu_tanh(float x) {
  return 0.5f * x * (1.0f + tanhf(0.7978845608028654f * (x + 0.044715f * x * x * x)));
}

__device__ __forceinline__ void stv(float* p, long i, float v) { p[i] = v; }
__device__ __forceinline__ void stv(bf16* p, long i, float v)  { p[i] = __float2bfloat16(v); }

// ---------------------------------------------------------------- GEMM
// C[M,N] = A[M,K] (bf16 row-major, leading dim lda)
//        x B'[N,K] (bf16 "B-transposed" row-major, leading dim ldb)
// batch z: off = (z/nH)*s?b + (z%nH)*s?h
// EPI: 0 = f32 store, 1 = bf16 store, 2 = f32 residual add, 3 = bf16 gelu store
template <int EPI>
__launch_bounds__(256)
__global__ void gemm_k(const bf16* __restrict__ A, int lda, long sAb, long sAh,
                       const bf16* __restrict__ Bt, int ldb, long sBb, long sBh,
                       void* __restrict__ Cp, int ldc, long sCb, long sCh,
                       const float* __restrict__ resid, int K, int nH) {
  __shared__ __align__(16) bf16 lsA[128 * 32];
  __shared__ __align__(16) bf16 lsB[128 * 32];
  const int tid = threadIdx.x;
  const int zb = blockIdx.z / nH, zh = blockIdx.z % nH;
  const int m0 = blockIdx.y * 128, n0 = blockIdx.x * 128;
  const int sr = tid >> 2, sc = (tid & 3) * 8;
  const bf16* Ag = A + zb * sAb + zh * sAh + (long)(m0 + sr) * lda + sc;
  const bf16* Bg = Bt + zb * sBb + zh * sBh + (long)(n0 + sr) * ldb + sc;
  const long a64 = 64L * lda, b64 = 64L * ldb;
  bf16* la0 = lsA + tid * 8;
  bf16* la1 = lsA + 2048 + tid * 8;
  bf16* lb0 = lsB + tid * 8;
  bf16* lb1 = lsB + 2048 + tid * 8;

  const int lane = tid & 63, wv = tid >> 6;
  const int wm = (wv >> 1) * 64, wn = (wv & 1) * 64;
  const int fl = lane & 15, fg = lane >> 4;

  f32x4 acc[4][4];
#pragma unroll
  for (int i = 0; i < 4; i++)
#pragma unroll
    for (int j = 0; j < 4; j++) acc[i][j] = (f32x4){0.f, 0.f, 0.f, 0.f};

  for (int k0 = 0; k0 < K; k0 += 32) {
    gll16(Ag + k0, la0);
    gll16(Ag + a64 + k0, la1);
    gll16(Bg + k0, lb0);
    gll16(Bg + b64 + k0, lb1);
    __syncthreads();
    s16x8 af[4], bq[4];
#pragma unroll
    for (int i = 0; i < 4; i++) {
      af[i] = *(const s16x8*)(lsA + (wm + i * 16 + fl) * 32 + fg * 8);
      bq[i] = *(const s16x8*)(lsB + (wn + i * 16 + fl) * 32 + fg * 8);
    }
#pragma unroll
    for (int i = 0; i < 4; i++)
#pragma unroll
      for (int j = 0; j < 4; j++)
        acc[i][j] = __builtin_amdgcn_mfma_f32_16x16x32_bf16(af[i], bq[j], acc[i][j], 0, 0, 0);
    __syncthreads();
  }

  const long offC = zb * sCb + zh * sCh;
#pragma unroll
  for (int i = 0; i < 4; i++) {
#pragma unroll
    for (int j = 0; j < 4; j++) {
      const int row = m0 + wm + i * 16 + fg * 4;
      const int col = n0 + wn + j * 16 + fl;
#pragma unroll
      for (int r = 0; r < 4; r++) {
        const long ci = offC + (long)(row + r) * ldc + col;
        float v = acc[i][j][r];
        if (EPI == 0) {
          ((float*)Cp)[ci] = v;
        } else if (EPI == 1) {
          ((bf16*)Cp)[ci] = __float2bfloat16(v);
        } else if (EPI == 2) {
          ((float*)Cp)[ci] = v + resid[ci];
        } else {
          ((bf16*)Cp)[ci] = __float2bfloat16(gelu_tanh(v));
        }
      }
    }
  }
}

// ------------------------------------------------- weight transpose + cast
// in: fp32 [R][C] row-major   out: bf16 [C][R] row-major
__launch_bounds__(256)
__global__ void transcast_k(const float* __restrict__ in, bf16* __restrict__ out,
                            int R, int C) {
  __shared__ float tile[32][33];
  const int tx = threadIdx.x, ty = threadIdx.y;
  const int c0 = blockIdx.x * 32, r0 = blockIdx.y * 32;
#pragma unroll
  for (int k = 0; k < 4; k++)
    tile[ty + 8 * k][tx] = in[(long)(r0 + ty + 8 * k) * C + c0 + tx];
  __syncthreads();
#pragma unroll
  for (int k = 0; k < 4; k++)
    out[(long)(c0 + ty + 8 * k) * R + r0 + tx] = __float2bfloat16(tile[tx][ty + 8 * k]);
}

// ------------------------------------------------- V transpose per head
// qkv bf16 [BS][3D]; V part -> Vt [BH][DH][S]
__launch_bounds__(256)
__global__ void vtrans_k(const bf16* __restrict__ qkv, bf16* __restrict__ Vt) {
  __shared__ bf16 tile[32][33];
  const int z = blockIdx.z, b = z / H, h = z % H;
  const int d0 = blockIdx.x * 32, s0 = blockIdx.y * 32;
  const int tx = threadIdx.x, ty = threadIdx.y;
#pragma unroll
  for (int k = 0; k < 4; k++)
    tile[ty + 8 * k][tx] =
        qkv[(long)(b * S + s0 + ty + 8 * k) * D3 + 2 * D + h * DH + d0 + tx];
  __syncthreads();
#pragma unroll
  for (int k = 0; k < 4; k++)
    Vt[((long)z * DH + d0 + ty + 8 * k) * S + s0 + tx] = tile[tx][ty + 8 * k];
}

// ---------------------------------------------------------------- LayerNorm
template <typename OutT>
__launch_bounds__(256)
__global__ void ln_k(const float* __restrict__ x, const float* __restrict__ g,
                     const float* __restrict__ bb, OutT* __restrict__ out) {
  __shared__ float sA[4], sB[4];
  const long row = blockIdx.x;
  const int tid = threadIdx.x;
  const float4* xr = (const float4*)(x + row * D);
  float4 v0 = xr[tid], v1 = xr[tid + 256];
  float s = v0.x + v0.y + v0.z + v0.w + v1.x + v1.y + v1.z + v1.w;
  float ss = v0.x * v0.x + v0.y * v0.y + v0.z * v0.z + v0.w * v0.w +
             v1.x * v1.x + v1.y * v1.y + v1.z * v1.z + v1.w * v1.w;
  s = wave_sum(s);
  ss = wave_sum(ss);
  const int lane = tid & 63, wv = tid >> 6;
  if (lane == 0) { sA[wv] = s; sB[wv] = ss; }
  __syncthreads();
  s = sA[0] + sA[1] + sA[2] + sA[3];
  ss = sB[0] + sB[1] + sB[2] + sB[3];
  const float mean = s * (1.f / D);
  const float var = ss * (1.f / D) - mean * mean;
  const float rstd = rsqrtf(var + 1e-5f);
  const float4* gv = (const float4*)g;
  const float4* bv = (const float4*)bb;
  float4 g0 = gv[tid], g1 = gv[tid + 256], c0 = bv[tid], c1 = bv[tid + 256];
  OutT* orow = out + row * D;
  stv(orow, 4 * tid + 0, (v0.x - mean) * rstd * g0.x + c0.x);
  stv(orow, 4 * tid + 1, (v0.y - mean) * rstd * g0.y + c0.y);
  stv(orow, 4 * tid + 2, (v0.z - mean) * rstd * g0.z + c0.z);
  stv(orow, 4 * tid + 3, (v0.w - mean) * rstd * g0.w + c0.w);
  stv(orow, 1024 + 4 * tid + 0, (v1.x - mean) * rstd * g1.x + c1.x);
  stv(orow, 1024 + 4 * tid + 1, (v1.y - mean) * rstd * g1.y + c1.y);
  stv(orow, 1024 + 4 * tid + 2, (v1.z - mean) * rstd * g1.z + c1.z);
  stv(orow, 1024 + 4 * tid + 3, (v1.w - mean) * rstd * g1.w + c1.w);
}

// ---------------------------------------------------------------- embedding
__launch_bounds__(256)
__global__ void embed_k(const int* __restrict__ ids, const float* __restrict__ emb,
                        float* __restrict__ x) {
  const long gid = (long)blockIdx.x * 256 + threadIdx.x;  // over BS * D/4
  const int tok = (int)(gid >> 9);                        // D/4 = 512
  const int c = (int)(gid & 511);
  const int id = ids[tok];
  ((float4*)x)[gid] = ((const float4*)(emb + (long)id * D))[c];
}

// ------------------------------------------- softmax (in-place fp32 -> bf16)
__launch_bounds__(256)
__global__ void softmax_k(float* __restrict__ scores, const int* __restrict__ amask,
                          float scale) {
  __shared__ float sred[4];
  const int q = blockIdx.x, z = blockIdx.y, b = z / H;
  float* row = scores + ((long)z * S + q) * S;
  const int tid = threadIdx.x;
  const int lane = tid & 63, wv = tid >> 6;
  float v[4];
  float mx = -3.4e38f;
#pragma unroll
  for (int i = 0; i < 4; i++) {
    const int k = tid + i * 256;
    const float s = row[k] * scale;
    const bool ok = (k <= q) && (amask[b * S + k] != 0);
    v[i] = s + (ok ? 0.f : -1e9f);
    mx = fmaxf(mx, v[i]);
  }
  mx = wave_max(mx);
  if (lane == 0) sred[wv] = mx;
  __syncthreads();
  mx = fmaxf(fmaxf(sred[0], sred[1]), fmaxf(sred[2], sred[3]));
  __syncthreads();
  float e[4], sm = 0.f;
#pragma unroll
  for (int i = 0; i < 4; i++) {
    e[i] = __expf(v[i] - mx);
    sm += e[i];
  }
  sm = wave_sum(sm);
  if (lane == 0) sred[wv] = sm;
  __syncthreads();
  sm = sred[0] + sred[1] + sred[2] + sred[3];
  const float inv = 1.f / sm;
  bf16* orow = (bf16*)row;  // in-place: all fp32 reads completed before barrier
#pragma unroll
  for (int i = 0; i < 4; i++) orow[tid + i * 256] = __float2bfloat16(e[i] * inv);
}

// ---------------------------------------------------------------- pooling
__launch_bounds__(256)
__global__ void pool_k(const float* __restrict__ hs, const int* __restrict__ amask,
                       float* __restrict__ pooled) {
  const int d = blockIdx.x * 256 + threadIdx.x;
  const int b = blockIdx.y;
  float s = 0.f, cnt = 0.f;
  for (int i = 0; i < S; i++) {
    const float m = (float)amask[b * S + i];
    s += hs[((long)(b * S + i)) * D + d] * m;
    cnt += m;
  }
  pooled[b * D + d] = s / fmaxf(cnt, 1e-9f);
}

// ---------------------------------------------------------------- head
__launch_bounds__(256)
__global__ void head1_k(const float* __restrict__ pooled, const float* __restrict__ Wc1,
                        const float* __restrict__ bc1, float* __restrict__ t) {
  const int j = blockIdx.x * 256 + threadIdx.x;
  const int b = blockIdx.y;
  float s = bc1[j];
  for (int d = 0; d < D; d++) s += pooled[b * D + d] * Wc1[(long)d * D + j];
  t[b * D + j] = tanhf(s);
}

__launch_bounds__(256)
__global__ void head2_k(const float* __restrict__ t, const float* __restrict__ Wc2,
                        const float* __restrict__ bc2, float* __restrict__ out) {
  __shared__ float red[4][4];
  const int tid = threadIdx.x;
  const int lane = tid & 63, wv = tid >> 6;
  float a[4] = {0.f, 0.f, 0.f, 0.f};  // [b*2+c]
  for (int j = tid; j < D; j += 256) {
    const float w0 = Wc2[j * 2 + 0], w1 = Wc2[j * 2 + 1];
    const float t0 = t[j], t1 = t[D + j];
    a[0] += t0 * w0; a[1] += t0 * w1; a[2] += t1 * w0; a[3] += t1 * w1;
  }
#pragma unroll
  for (int c = 0; c < 4; c++) a[c] = wave_sum(a[c]);
  if (lane == 0) {
#pragma unroll
    for (int c = 0; c < 4; c++) red[wv][c] = a[c];
  }
  __syncthreads();
  if (tid == 0) {
    float tot[4];
#pragma unroll
    for (int c = 0; c < 4; c++) tot[c] = red[0][c] + red[1][c] + red[2][c] + red[3][c];
    const float l00 = tot[0] + bc2[0], l01 = tot[1] + bc2[1];
    const float l10 = tot[2] + bc2[0], l11 = tot[3] + bc2[1];
    out[0] = 1.f / (1.f + __expf(l00 - l01));
    out[1] = 1.f / (1.f + __expf(l10 - l11));
  }
}

// ---------------------------------------------------------------- launcher
extern "C" void kernel_launch(void* const* d_in, const int* in_sizes, int n_in,
                              void* d_out, int out_size, void* d_ws, size_t ws_size,
                              hipStream_t stream) {
  (void)in_sizes; (void)n_in; (void)out_size; (void)ws_size;
  const int*   ids   = (const int*)d_in[0];
  const int*   amask = (const int*)d_in[1];
  const float* emb   = (const float*)d_in[2];
  const float* ln1g  = (const float*)d_in[3];
  const float* ln1b  = (const float*)d_in[4];
  const float* Wqkv  = (const float*)d_in[5];
  const float* Wo    = (const float*)d_in[6];
  const float* ln2g  = (const float*)d_in[7];
  const float* ln2b  = (const float*)d_in[8];
  const float* W1    = (const float*)d_in[9];
  const float* W2    = (const float*)d_in[10];
  const float* lnfg  = (const float*)d_in[11];
  const float* lnfb  = (const float*)d_in[12];
  const float* Wc1   = (const float*)d_in[13];
  const float* bc1   = (const float*)d_in[14];
  const float* Wc2   = (const float*)d_in[15];
  const float* bc2   = (const float*)d_in[16];
  float* out = (float*)d_out;

  char* ws = (char*)d_ws;
  size_t off = 0;
  auto alloc = [&](size_t bytes) {
    size_t r = off;
    off += (bytes + 255) & ~(size_t)255;
    return r;
  };
  // per-layer bf16-transposed weights (overwritten each layer)
  bf16* Wqkv_t = (bf16*)(ws + alloc((size_t)D3 * D * 2));
  bf16* Wo_t   = (bf16*)(ws + alloc((size_t)D * D * 2));
  bf16* W1_t   = (bf16*)(ws + alloc((size_t)FF * D * 2));
  bf16* W2_t   = (bf16*)(ws + alloc((size_t)D * FF * 2));
  float* x     = (float*)(ws + alloc((size_t)BS * D * 4));
  bf16* h      = (bf16*)(ws + alloc((size_t)BS * D * 2));
  bf16* qkv    = (bf16*)(ws + alloc((size_t)BS * D3 * 2));
  bf16* Vt     = (bf16*)(ws + alloc((size_t)BH * DH * S * 2));
  bf16* o_buf  = (bf16*)(ws + alloc((size_t)BS * D * 2));
  float* pooled= (float*)(ws + alloc((size_t)NB * D * 4));
  float* tb    = (float*)(ws + alloc((size_t)NB * D * 4));
  char* big    = ws + alloc((size_t)BH * S * S * 4);  // scores / ff / hs union
  float* scores = (float*)big;
  bf16*  ffb    = (bf16*)big;
  float* hs     = (float*)big;

  const float scale = 0.088388347648318447f;  // 1/sqrt(128)
  dim3 blk(256);
  dim3 tblk(32, 8);

  embed_k<<<4096, blk, 0, stream>>>(ids, emb, x);

  for (int l = 0; l < L; l++) {
    // weight prep for this layer
    transcast_k<<<dim3(D3 / 32, D / 32), tblk, 0, stream>>>(Wqkv + (size_t)l * D * D3, Wqkv_t, D, D3);
    transcast_k<<<dim3(D / 32, D / 32), tblk, 0, stream>>>(Wo + (size_t)l * D * D, Wo_t, D, D);
    transcast_k<<<dim3(FF / 32, D / 32), tblk, 0, stream>>>(W1 + (size_t)l * D * FF, W1_t, D, FF);
    transcast_k<<<dim3(D / 32, FF / 32), tblk, 0, stream>>>(W2 + (size_t)l * FF * D, W2_t, FF, D);

    // h = LN1(x)
    ln_k<bf16><<<BS, blk, 0, stream>>>(x, ln1g + (size_t)l * D, ln1b + (size_t)l * D, h);
    // qkv = h @ Wqkv
    gemm_k<1><<<dim3(D3 / 128, BS / 128, 1), blk, 0, stream>>>(
        h, D, 0, 0, Wqkv_t, D, 0, 0, qkv, D3, 0, 0, nullptr, D, 1);
    // Vt
    vtrans_k<<<dim3(DH / 32, S / 32, BH), tblk, 0, stream>>>(qkv, Vt);
    // scores = Q @ K^T  (per b,h)
    gemm_k<0><<<dim3(S / 128, S / 128, BH), blk, 0, stream>>>(
        qkv, D3, (long)S * D3, DH,
        qkv + D, D3, (long)S * D3, DH,
        scores, S, (long)H * S * S, (long)S * S, nullptr, DH, H);
    // softmax (scale + causal/pad mask), in-place fp32 -> bf16
    softmax_k<<<dim3(S, BH), blk, 0, stream>>>(scores, amask, scale);
    // o = attn @ V  (per b,h); attn rows are bf16 packed at stride 2S elements
    gemm_k<1><<<dim3(DH / 128, S / 128, BH), blk, 0, stream>>>(
        (const bf16*)scores, 2 * S, (long)H * 2 * S * S, (long)2 * S * S,
        Vt, S, (long)H * DH * S, (long)DH * S,
        o_buf, D, (long)S * D, DH, nullptr, S, H);
    // x = x + o @ Wo
    gemm_k<2><<<dim3(D / 128, BS / 128, 1), blk, 0, stream>>>(
        o_buf, D, 0, 0, Wo_t, D, 0, 0, x, D, 0, 0, x, D, 1);
    // h = LN2(x)
    ln_k<bf16><<<BS, blk, 0, stream>>>(x, ln2g + (size_t)l * D, ln2b + (size_t)l * D, h);
    // ff = gelu(h @ W1)
    gemm_k<3><<<dim3(FF / 128, BS / 128, 1), blk, 0, stream>>>(
        h, D, 0, 0, W1_t, D, 0, 0, ffb, FF, 0, 0, nullptr, D, 1);
    // x = x + ff @ W2
    gemm_k<2><<<dim3(D / 128, BS / 128, 1), blk, 0, stream>>>(
        ffb, FF, 0, 0, W2_t, FF, 0, 0, x, D, 0, 0, x, FF, 1);
  }

  // final LN -> hs (fp32), masked mean pool, classifier head
  ln_k<float><<<BS, blk, 0, stream>>>(x, lnfg, lnfb, hs);
  pool_k<<<dim3(D / 256, NB), blk, 0, stream>>>(hs, amask, pooled);
  head1_k<<<dim3(D / 256, NB), blk, 0, stream>>>(pooled, Wc1, bc1, tb);
  head2_k<<<1, blk, 0, stream>>>(tb, Wc2, bc2, out);
}

// Round 2
// 1745.832 us; speedup vs baseline: 1.1621x; 1.1621x over previous
//
#include <hip/hip_runtime.h>
#include <hip/hip_bf16.h>

using bf16 = __hip_bfloat16;
typedef short s16x8 __attribute__((ext_vector_type(8)));
typedef float f32x4 __attribute__((ext_vector_type(4)));

static constexpr int D  = 2048;
static constexpr int H  = 16;
static constexpr int FF = 8192;
static constexpr int S  = 1024;
static constexpr int NB = 2;        // batch
static constexpr int DH = 128;
static constexpr int L  = 2;
static constexpr int BS = NB * S;   // 2048 tokens
static constexpr int BH = NB * H;   // 32
static constexpr int D3 = 3 * D;    // 6144

// ---------------------------------------------------------------- utilities
__device__ __forceinline__ float wave_sum(float v) {
#pragma unroll
  for (int o = 32; o > 0; o >>= 1) v += __shfl_down(v, o, 64);
  return v;
}
__device__ __forceinline__ float wave_max(float v) {
#pragma unroll
  for (int o = 32; o > 0; o >>= 1) v = fmaxf(v, __shfl_down(v, o, 64));
  return v;
}

__device__ __forceinline__ void gll16(const void* g, void* l) {
  __builtin_amdgcn_global_load_lds(
      (const __attribute__((address_space(1))) unsigned int*)g,
      (__attribute__((address_space(3))) unsigned int*)l, 16, 0, 0);
}

__device__ __forceinline__ float gelu_tanh(float x) {
  return 0.5f * x * (1.0f + tanhf(0.7978845608028654f * (x + 0.044715f * x * x * x)));
}

__device__ __forceinline__ void stv(float* p, long i, float v) { p[i] = v; }
__device__ __forceinline__ void stv(bf16* p, long i, float v)  { p[i] = __float2bfloat16(v); }

// ---------------------------------------------------------------- GEMM
// C[M,N] = A[M,K] (bf16 row-major, leading dim lda)
//        x B'[N,K] (bf16 "B-transposed" row-major, leading dim ldb)
// batch z: off = (z/nH)*s?b + (z%nH)*s?h
// EPI: 0 = f32 store, 1 = bf16 store, 2 = f32 residual add, 3 = bf16 gelu store
// Double-buffered LDS K-loop: prefetch tile k+1 issued before compute on tile
// k; the vmcnt(0) drain at __syncthreads then only pays residual latency.
template <int EPI>
__launch_bounds__(256)
__global__ void gemm_k(const bf16* __restrict__ A, int lda, long sAb, long sAh,
                       const bf16* __restrict__ Bt, int ldb, long sBb, long sBh,
                       void* __restrict__ Cp, int ldc, long sCb, long sCh,
                       const float* __restrict__ resid, int K, int nH) {
  __shared__ __align__(16) bf16 lsA[2][128 * 32];
  __shared__ __align__(16) bf16 lsB[2][128 * 32];
  const int tid = threadIdx.x;
  const int zb = blockIdx.z / nH, zh = blockIdx.z % nH;
  const int m0 = blockIdx.y * 128, n0 = blockIdx.x * 128;
  const int sr = tid >> 2, sc = (tid & 3) * 8;
  const bf16* Ag = A + zb * sAb + zh * sAh + (long)(m0 + sr) * lda + sc;
  const bf16* Bg = Bt + zb * sBb + zh * sBh + (long)(n0 + sr) * ldb + sc;
  const long a64 = 64L * lda, b64 = 64L * ldb;

  const int lane = tid & 63, wv = tid >> 6;
  const int wm = (wv >> 1) * 64, wn = (wv & 1) * 64;
  const int fl = lane & 15, fg = lane >> 4;

  f32x4 acc[4][4];
#pragma unroll
  for (int i = 0; i < 4; i++)
#pragma unroll
    for (int j = 0; j < 4; j++) acc[i][j] = (f32x4){0.f, 0.f, 0.f, 0.f};

  // prologue: fill buffer 0
  gll16(Ag, lsA[0] + tid * 8);
  gll16(Ag + a64, lsA[0] + 2048 + tid * 8);
  gll16(Bg, lsB[0] + tid * 8);
  gll16(Bg + b64, lsB[0] + 2048 + tid * 8);
  __syncthreads();

  int it = 0;
  for (int k0 = 0; k0 < K; k0 += 32, it ^= 1) {
    const int nxt = it ^ 1;
    if (k0 + 32 < K) {
      gll16(Ag + k0 + 32, lsA[nxt] + tid * 8);
      gll16(Ag + a64 + k0 + 32, lsA[nxt] + 2048 + tid * 8);
      gll16(Bg + k0 + 32, lsB[nxt] + tid * 8);
      gll16(Bg + b64 + k0 + 32, lsB[nxt] + 2048 + tid * 8);
    }
    s16x8 af[4], bq[4];
#pragma unroll
    for (int i = 0; i < 4; i++) {
      af[i] = *(const s16x8*)(lsA[it] + (wm + i * 16 + fl) * 32 + fg * 8);
      bq[i] = *(const s16x8*)(lsB[it] + (wn + i * 16 + fl) * 32 + fg * 8);
    }
#pragma unroll
    for (int i = 0; i < 4; i++)
#pragma unroll
      for (int j = 0; j < 4; j++)
        acc[i][j] = __builtin_amdgcn_mfma_f32_16x16x32_bf16(af[i], bq[j], acc[i][j], 0, 0, 0);
    __syncthreads();
  }

  const long offC = zb * sCb + zh * sCh;
#pragma unroll
  for (int i = 0; i < 4; i++) {
#pragma unroll
    for (int j = 0; j < 4; j++) {
      const int row = m0 + wm + i * 16 + fg * 4;
      const int col = n0 + wn + j * 16 + fl;
#pragma unroll
      for (int r = 0; r < 4; r++) {
        const long ci = offC + (long)(row + r) * ldc + col;
        float v = acc[i][j][r];
        if (EPI == 0) {
          ((float*)Cp)[ci] = v;
        } else if (EPI == 1) {
          ((bf16*)Cp)[ci] = __float2bfloat16(v);
        } else if (EPI == 2) {
          ((float*)Cp)[ci] = v + resid[ci];
        } else {
          ((bf16*)Cp)[ci] = __float2bfloat16(gelu_tanh(v));
        }
      }
    }
  }
}

// --------------------------------------------- split-K reduce: x += sum(p[0..3])
__launch_bounds__(256)
__global__ void reduce4_k(const float* __restrict__ p, float* __restrict__ x) {
  const long i = (long)blockIdx.x * 256 + threadIdx.x;  // over BS*D/4 float4s
  const long n = (long)BS * D / 4;
  const float4 a = ((const float4*)p)[i];
  const float4 b = ((const float4*)p)[i + n];
  const float4 c = ((const float4*)p)[i + 2 * n];
  const float4 d2 = ((const float4*)p)[i + 3 * n];
  float4 xv = ((float4*)x)[i];
  xv.x += a.x + b.x + c.x + d2.x;
  xv.y += a.y + b.y + c.y + d2.y;
  xv.z += a.z + b.z + c.z + d2.z;
  xv.w += a.w + b.w + c.w + d2.w;
  ((float4*)x)[i] = xv;
}

// ------------------------------------------------- weight transpose + cast
// in: fp32 [R][C] row-major   out: bf16 [C][R] row-major
__launch_bounds__(256)
__global__ void transcast_k(const float* __restrict__ in, bf16* __restrict__ out,
                            int R, int C) {
  __shared__ float tile[32][33];
  const int tx = threadIdx.x, ty = threadIdx.y;
  const int c0 = blockIdx.x * 32, r0 = blockIdx.y * 32;
#pragma unroll
  for (int k = 0; k < 4; k++)
    tile[ty + 8 * k][tx] = in[(long)(r0 + ty + 8 * k) * C + c0 + tx];
  __syncthreads();
#pragma unroll
  for (int k = 0; k < 4; k++)
    out[(long)(c0 + ty + 8 * k) * R + r0 + tx] = __float2bfloat16(tile[tx][ty + 8 * k]);
}

// ------------------------------------------------- V transpose per head
// qkv bf16 [BS][3D]; V part -> Vt [BH][DH][S]
__launch_bounds__(256)
__global__ void vtrans_k(const bf16* __restrict__ qkv, bf16* __restrict__ Vt) {
  __shared__ bf16 tile[32][33];
  const int z = blockIdx.z, b = z / H, h = z % H;
  const int d0 = blockIdx.x * 32, s0 = blockIdx.y * 32;
  const int tx = threadIdx.x, ty = threadIdx.y;
#pragma unroll
  for (int k = 0; k < 4; k++)
    tile[ty + 8 * k][tx] =
        qkv[(long)(b * S + s0 + ty + 8 * k) * D3 + 2 * D + h * DH + d0 + tx];
  __syncthreads();
#pragma unroll
  for (int k = 0; k < 4; k++)
    Vt[((long)z * DH + d0 + ty + 8 * k) * S + s0 + tx] = tile[tx][ty + 8 * k];
}

// ---------------------------------------------------------------- LayerNorm
template <typename OutT>
__launch_bounds__(256)
__global__ void ln_k(const float* __restrict__ x, const float* __restrict__ g,
                     const float* __restrict__ bb, OutT* __restrict__ out) {
  __shared__ float sA[4], sB[4];
  const long row = blockIdx.x;
  const int tid = threadIdx.x;
  const float4* xr = (const float4*)(x + row * D);
  float4 v0 = xr[tid], v1 = xr[tid + 256];
  float s = v0.x + v0.y + v0.z + v0.w + v1.x + v1.y + v1.z + v1.w;
  float ss = v0.x * v0.x + v0.y * v0.y + v0.z * v0.z + v0.w * v0.w +
             v1.x * v1.x + v1.y * v1.y + v1.z * v1.z + v1.w * v1.w;
  s = wave_sum(s);
  ss = wave_sum(ss);
  const int lane = tid & 63, wv = tid >> 6;
  if (lane == 0) { sA[wv] = s; sB[wv] = ss; }
  __syncthreads();
  s = sA[0] + sA[1] + sA[2] + sA[3];
  ss = sB[0] + sB[1] + sB[2] + sB[3];
  const float mean = s * (1.f / D);
  const float var = ss * (1.f / D) - mean * mean;
  const float rstd = rsqrtf(var + 1e-5f);
  const float4* gv = (const float4*)g;
  const float4* bv = (const float4*)bb;
  float4 g0 = gv[tid], g1 = gv[tid + 256], c0 = bv[tid], c1 = bv[tid + 256];
  OutT* orow = out + row * D;
  stv(orow, 4 * tid + 0, (v0.x - mean) * rstd * g0.x + c0.x);
  stv(orow, 4 * tid + 1, (v0.y - mean) * rstd * g0.y + c0.y);
  stv(orow, 4 * tid + 2, (v0.z - mean) * rstd * g0.z + c0.z);
  stv(orow, 4 * tid + 3, (v0.w - mean) * rstd * g0.w + c0.w);
  stv(orow, 1024 + 4 * tid + 0, (v1.x - mean) * rstd * g1.x + c1.x);
  stv(orow, 1024 + 4 * tid + 1, (v1.y - mean) * rstd * g1.y + c1.y);
  stv(orow, 1024 + 4 * tid + 2, (v1.z - mean) * rstd * g1.z + c1.z);
  stv(orow, 1024 + 4 * tid + 3, (v1.w - mean) * rstd * g1.w + c1.w);
}

// ---------------------------------------------------------------- embedding
__launch_bounds__(256)
__global__ void embed_k(const int* __restrict__ ids, const float* __restrict__ emb,
                        float* __restrict__ x) {
  const long gid = (long)blockIdx.x * 256 + threadIdx.x;  // over BS * D/4
  const int tok = (int)(gid >> 9);                        // D/4 = 512
  const int c = (int)(gid & 511);
  const int id = ids[tok];
  ((float4*)x)[gid] = ((const float4*)(emb + (long)id * D))[c];
}

// ------------------------------------------- softmax (in-place fp32 -> bf16)
__launch_bounds__(256)
__global__ void softmax_k(float* __restrict__ scores, const int* __restrict__ amask,
                          float scale) {
  __shared__ float sred[4];
  const int q = blockIdx.x, z = blockIdx.y, b = z / H;
  float* row = scores + ((long)z * S + q) * S;
  const int tid = threadIdx.x;
  const int lane = tid & 63, wv = tid >> 6;
  float v[4];
  float mx = -3.4e38f;
#pragma unroll
  for (int i = 0; i < 4; i++) {
    const int k = tid + i * 256;
    const float s = row[k] * scale;
    const bool ok = (k <= q) && (amask[b * S + k] != 0);
    v[i] = s + (ok ? 0.f : -1e9f);
    mx = fmaxf(mx, v[i]);
  }
  mx = wave_max(mx);
  if (lane == 0) sred[wv] = mx;
  __syncthreads();
  mx = fmaxf(fmaxf(sred[0], sred[1]), fmaxf(sred[2], sred[3]));
  __syncthreads();
  float e[4], sm = 0.f;
#pragma unroll
  for (int i = 0; i < 4; i++) {
    e[i] = __expf(v[i] - mx);
    sm += e[i];
  }
  sm = wave_sum(sm);
  if (lane == 0) sred[wv] = sm;
  __syncthreads();
  sm = sred[0] + sred[1] + sred[2] + sred[3];
  const float inv = 1.f / sm;
  bf16* orow = (bf16*)row;  // in-place: all fp32 reads completed before barrier
#pragma unroll
  for (int i = 0; i < 4; i++) orow[tid + i * 256] = __float2bfloat16(e[i] * inv);
}

// ---------------------------------------------------------------- pooling
__launch_bounds__(256)
__global__ void pool_k(const float* __restrict__ hs, const int* __restrict__ amask,
                       float* __restrict__ pooled) {
  const int d = blockIdx.x * 256 + threadIdx.x;
  const int b = blockIdx.y;
  float s = 0.f, cnt = 0.f;
  for (int i = 0; i < S; i++) {
    const float m = (float)amask[b * S + i];
    s += hs[((long)(b * S + i)) * D + d] * m;
    cnt += m;
  }
  pooled[b * D + d] = s / fmaxf(cnt, 1e-9f);
}

// ---------------------------------------------------------------- head
__launch_bounds__(256)
__global__ void head1_k(const float* __restrict__ pooled, const float* __restrict__ Wc1,
                        const float* __restrict__ bc1, float* __restrict__ t) {
  const int j = blockIdx.x * 256 + threadIdx.x;
  const int b = blockIdx.y;
  float s = bc1[j];
  for (int d = 0; d < D; d++) s += pooled[b * D + d] * Wc1[(long)d * D + j];
  t[b * D + j] = tanhf(s);
}

__launch_bounds__(256)
__global__ void head2_k(const float* __restrict__ t, const float* __restrict__ Wc2,
                        const float* __restrict__ bc2, float* __restrict__ out) {
  __shared__ float red[4][4];
  const int tid = threadIdx.x;
  const int lane = tid & 63, wv = tid >> 6;
  float a[4] = {0.f, 0.f, 0.f, 0.f};  // [b*2+c]
  for (int j = tid; j < D; j += 256) {
    const float w0 = Wc2[j * 2 + 0], w1 = Wc2[j * 2 + 1];
    const float t0 = t[j], t1 = t[D + j];
    a[0] += t0 * w0; a[1] += t0 * w1; a[2] += t1 * w0; a[3] += t1 * w1;
  }
#pragma unroll
  for (int c = 0; c < 4; c++) a[c] = wave_sum(a[c]);
  if (lane == 0) {
#pragma unroll
    for (int c = 0; c < 4; c++) red[wv][c] = a[c];
  }
  __syncthreads();
  if (tid == 0) {
    float tot[4];
#pragma unroll
    for (int c = 0; c < 4; c++) tot[c] = red[0][c] + red[1][c] + red[2][c] + red[3][c];
    const float l00 = tot[0] + bc2[0], l01 = tot[1] + bc2[1];
    const float l10 = tot[2] + bc2[0], l11 = tot[3] + bc2[1];
    out[0] = 1.f / (1.f + __expf(l00 - l01));
    out[1] = 1.f / (1.f + __expf(l10 - l11));
  }
}

// ---------------------------------------------------------------- launcher
extern "C" void kernel_launch(void* const* d_in, const int* in_sizes, int n_in,
                              void* d_out, int out_size, void* d_ws, size_t ws_size,
                              hipStream_t stream) {
  (void)in_sizes; (void)n_in; (void)out_size; (void)ws_size;
  const int*   ids   = (const int*)d_in[0];
  const int*   amask = (const int*)d_in[1];
  const float* emb   = (const float*)d_in[2];
  const float* ln1g  = (const float*)d_in[3];
  const float* ln1b  = (const float*)d_in[4];
  const float* Wqkv  = (const float*)d_in[5];
  const float* Wo    = (const float*)d_in[6];
  const float* ln2g  = (const float*)d_in[7];
  const float* ln2b  = (const float*)d_in[8];
  const float* W1    = (const float*)d_in[9];
  const float* W2    = (const float*)d_in[10];
  const float* lnfg  = (const float*)d_in[11];
  const float* lnfb  = (const float*)d_in[12];
  const float* Wc1   = (const float*)d_in[13];
  const float* bc1   = (const float*)d_in[14];
  const float* Wc2   = (const float*)d_in[15];
  const float* bc2   = (const float*)d_in[16];
  float* out = (float*)d_out;

  char* ws = (char*)d_ws;
  size_t off = 0;
  auto alloc = [&](size_t bytes) {
    size_t r = off;
    off += (bytes + 255) & ~(size_t)255;
    return r;
  };
  // per-layer bf16-transposed weights (overwritten each layer)
  bf16* Wqkv_t = (bf16*)(ws + alloc((size_t)D3 * D * 2));
  bf16* Wo_t   = (bf16*)(ws + alloc((size_t)D * D * 2));
  bf16* W1_t   = (bf16*)(ws + alloc((size_t)FF * D * 2));
  bf16* W2_t   = (bf16*)(ws + alloc((size_t)D * FF * 2));
  float* x     = (float*)(ws + alloc((size_t)BS * D * 4));
  bf16* h      = (bf16*)(ws + alloc((size_t)BS * D * 2));
  bf16* qkv    = (bf16*)(ws + alloc((size_t)BS * D3 * 2));
  bf16* Vt     = (bf16*)(ws + alloc((size_t)BH * DH * S * 2));
  bf16* o_buf  = (bf16*)(ws + alloc((size_t)BS * D * 2));
  float* pooled= (float*)(ws + alloc((size_t)NB * D * 4));
  float* tb    = (float*)(ws + alloc((size_t)NB * D * 4));
  char* big    = ws + alloc((size_t)BH * S * S * 4);  // scores / ff+partials / hs union
  float* scores = (float*)big;
  bf16*  ffb    = (bf16*)big;                          // [BS][FF] bf16 = 33.5 MB
  float* hs     = (float*)big;
  // split-K partials: 4 x [BS][D] fp32 = 64 MB, placed after ffb inside big
  float* parts  = (float*)(big + ((size_t)BS * FF * 2 + 255 & ~(size_t)255));

  const float scale = 0.088388347648318447f;  // 1/sqrt(128)
  dim3 blk(256);
  dim3 tblk(32, 8);

  embed_k<<<4096, blk, 0, stream>>>(ids, emb, x);

  for (int l = 0; l < L; l++) {
    // weight prep for this layer
    transcast_k<<<dim3(D3 / 32, D / 32), tblk, 0, stream>>>(Wqkv + (size_t)l * D * D3, Wqkv_t, D, D3);
    transcast_k<<<dim3(D / 32, D / 32), tblk, 0, stream>>>(Wo + (size_t)l * D * D, Wo_t, D, D);
    transcast_k<<<dim3(FF / 32, D / 32), tblk, 0, stream>>>(W1 + (size_t)l * D * FF, W1_t, D, FF);
    transcast_k<<<dim3(D / 32, FF / 32), tblk, 0, stream>>>(W2 + (size_t)l * FF * D, W2_t, FF, D);

    // h = LN1(x)
    ln_k<bf16><<<BS, blk, 0, stream>>>(x, ln1g + (size_t)l * D, ln1b + (size_t)l * D, h);
    // qkv = h @ Wqkv
    gemm_k<1><<<dim3(D3 / 128, BS / 128, 1), blk, 0, stream>>>(
        h, D, 0, 0, Wqkv_t, D, 0, 0, qkv, D3, 0, 0, nullptr, D, 1);
    // Vt
    vtrans_k<<<dim3(DH / 32, S / 32, BH), tblk, 0, stream>>>(qkv, Vt);
    // scores = Q @ K^T  (per b,h)
    gemm_k<0><<<dim3(S / 128, S / 128, BH), blk, 0, stream>>>(
        qkv, D3, (long)S * D3, DH,
        qkv + D, D3, (long)S * D3, DH,
        scores, S, (long)H * S * S, (long)S * S, nullptr, DH, H);
    // softmax (scale + causal/pad mask), in-place fp32 -> bf16
    softmax_k<<<dim3(S, BH), blk, 0, stream>>>(scores, amask, scale);
    // o = attn @ V  (per b,h); attn rows are bf16 packed at stride 2S elements
    gemm_k<1><<<dim3(DH / 128, S / 128, BH), blk, 0, stream>>>(
        (const bf16*)scores, 2 * S, (long)H * 2 * S * S, (long)2 * S * S,
        Vt, S, (long)H * DH * S, (long)DH * S,
        o_buf, D, (long)S * D, DH, nullptr, S, H);
    // x = x + o @ Wo
    gemm_k<2><<<dim3(D / 128, BS / 128, 1), blk, 0, stream>>>(
        o_buf, D, 0, 0, Wo_t, D, 0, 0, x, D, 0, 0, x, D, 1);
    // h = LN2(x)
    ln_k<bf16><<<BS, blk, 0, stream>>>(x, ln2g + (size_t)l * D, ln2b + (size_t)l * D, h);
    // ff = gelu(h @ W1)
    gemm_k<3><<<dim3(FF / 128, BS / 128, 1), blk, 0, stream>>>(
        h, D, 0, 0, W1_t, D, 0, 0, ffb, FF, 0, 0, nullptr, D, 1);
    // x = x + ff @ W2 -- split-K=4: grid 16x16x4 = 1024 blocks (4/CU), fp32
    // partials then vectorized reduce. zh selects K-chunk of 2048.
    gemm_k<0><<<dim3(D / 128, BS / 128, 4), blk, 0, stream>>>(
        ffb, FF, 0, 2048, W2_t, FF, 0, 2048,
        parts, D, 0, (long)BS * D, nullptr, 2048, 4);
    reduce4_k<<<dim3(BS * D / 4 / 256), blk, 0, stream>>>(parts, x);
  }

  // final LN -> hs (fp32), masked mean pool, classifier head
  ln_k<float><<<BS, blk, 0, stream>>>(x, lnfg, lnfb, hs);
  pool_k<<<dim3(D / 256, NB), blk, 0, stream>>>(hs, amask, pooled);
  head1_k<<<dim3(D / 256, NB), blk, 0, stream>>>(pooled, Wc1, bc1, tb);
  head2_k<<<1, blk, 0, stream>>>(tb, Wc2, bc2, out);
}